// Round 6
// baseline (158.598 us; speedup 1.0000x reference)
//
#include <hip/hip_runtime.h>

// AdaptiveGN_Patches_Hadamart: per-patch GroupNorm + silu-gate, fp32.
// R5: no LDS staging. Each block = one (b, pi, pj, group) = 4 ch x 64x64
// patch. x is read TWICE — the 64 KB tile's second read is served by
// L1/L2/L3 (R0 measured FETCH unchanged), which costs no HBM traffic and
// frees all LDS -> 4 blocks/CU (launch_bounds(512,8)), 2x latency hiding
// vs the 64 KB-LDS version's 2 blocks/CU. NT stores keep `out` from
// evicting x tiles from L2 between the two reads.
// Per-thread addresses are a0 + compile-time offsets:
//   u = tid + k*512, cc = k>>1, f4row offset = (k&1)*8192, so
//   a = a0 + (k>>1)*65536 + (k&1)*8192,  a0 = base + (tid>>4)*256 + (tid&15)*4

constexpr int CHANNELS = 128;
constexpr int HW = 256;
constexpr int NP = 4;
constexpr int G = 32;
constexpr int CPG = CHANNELS / G;          // 4 channels per group
constexpr float EPS = 1e-5f;

typedef float f32x4 __attribute__((ext_vector_type(4)));

__device__ __forceinline__ float fast_gate(float v) {
    // 1 + silu(v) = 1 + v / (1 + exp(-v)); exp(-v) = exp2(-v*log2(e))
    const float e = __builtin_amdgcn_exp2f(v * -1.44269504088896f);
    return 1.0f + v * __builtin_amdgcn_rcpf(1.0f + e);
}

__global__ __launch_bounds__(512, 8)
void gn_patch_gate_kernel(const float* __restrict__ x,
                          const float* __restrict__ y,
                          const float* __restrict__ wgt,
                          const float* __restrict__ bvec,
                          float* __restrict__ out)
{
    __shared__ float red[16];

    const int bid = blockIdx.x;
    const int g  = bid & 31;          // group
    const int pj = (bid >> 5) & 3;    // patch col
    const int pi = (bid >> 7) & 3;    // patch row
    const int b  = bid >> 9;          // batch
    const int tid = threadIdx.x;

    const unsigned cstride = HW * HW; // 65536 floats per channel plane
    const unsigned base =
        (((unsigned)b * CHANNELS + (unsigned)g * CPG) * HW + (unsigned)pi * 64) * HW
        + (unsigned)pj * 64;
    // thread-fixed base: row = tid>>4 (32 rows covered by 512 thr per half-
    // plane), col4 = tid&15
    const unsigned a0 = base + (((unsigned)tid >> 4) << 8) + (((unsigned)tid & 15) << 2);

    // Phase 1: stream x, accumulate sum / sumsq. Offsets are compile-time.
    float s = 0.f, ss = 0.f;
#pragma unroll
    for (int k = 0; k < 8; ++k) {
        const unsigned a = a0 + (unsigned)((k >> 1) * 65536 + (k & 1) * 8192);
        const float4 v = *reinterpret_cast<const float4*>(x + a);
        s  += (v.x + v.y) + (v.z + v.w);
        ss += (v.x * v.x + v.y * v.y) + (v.z * v.z + v.w * v.w);
    }

    // Wave (64-lane) butterfly reduce, then cross-wave via LDS.
#pragma unroll
    for (int off = 32; off; off >>= 1) {
        s  += __shfl_xor(s, off);
        ss += __shfl_xor(ss, off);
    }
    const int wv = tid >> 6;
    if ((tid & 63) == 0) { red[wv] = s; red[8 + wv] = ss; }
    __syncthreads();
    float ts = 0.f, tss = 0.f;
#pragma unroll
    for (int q = 0; q < 8; ++q) { ts += red[q]; tss += red[8 + q]; }

    const float inv_n = 1.0f / 16384.0f;
    const float mean = ts * inv_n;
    const float var  = fmaxf(tss * inv_n - mean * mean, 0.f);
    const float rstd = rsqrtf(var + EPS);

    // Per-channel affine folded into scale/shift (cc = k>>1 is static).
    float scl[CPG], sft[CPG];
#pragma unroll
    for (int cc = 0; cc < CPG; ++cc) {
        const float wc = wgt[g * CPG + cc];
        scl[cc] = wc * rstd;
        sft[cc] = bvec[g * CPG + cc] - mean * rstd * wc;
    }

    // Phase 2: re-read x (L1/L2-hit), read y, normalize+gate, NT store.
#pragma unroll
    for (int k = 0; k < 8; ++k) {
        const unsigned a = a0 + (unsigned)((k >> 1) * 65536 + (k & 1) * 8192);
        const int cc = k >> 1;
        const float4 v = *reinterpret_cast<const float4*>(x + a);
        const float4 w = *reinterpret_cast<const float4*>(y + a);
        f32x4 o;
        o.x = (v.x * scl[cc] + sft[cc]) * fast_gate(w.x);
        o.y = (v.y * scl[cc] + sft[cc]) * fast_gate(w.y);
        o.z = (v.z * scl[cc] + sft[cc]) * fast_gate(w.z);
        o.w = (v.w * scl[cc] + sft[cc]) * fast_gate(w.w);
        __builtin_nontemporal_store(o, reinterpret_cast<f32x4*>(out + a));
    }
}

extern "C" void kernel_launch(void* const* d_in, const int* in_sizes, int n_in,
                              void* d_out, int out_size, void* d_ws, size_t ws_size,
                              hipStream_t stream) {
    const float* x    = (const float*)d_in[0];
    const float* y    = (const float*)d_in[1];
    const float* wgt  = (const float*)d_in[2];
    const float* bvec = (const float*)d_in[3];
    float* out = (float*)d_out;

    const int B = in_sizes[0] / (CHANNELS * HW * HW);   // 8
    const int nblocks = B * NP * NP * G;                // 4096
    gn_patch_gate_kernel<<<dim3(nblocks), dim3(512), 0, stream>>>(x, y, wgt, bvec, out);
}

// Round 7
// 147.538 us; speedup vs baseline: 1.0750x; 1.0750x over previous
//
#include <hip/hip_runtime.h>

// AdaptiveGN_Patches_Hadamart: per-patch GroupNorm + silu-gate, fp32.
// R6: back to LDS staging (R5 proved the x re-read costs +128 MB real HBM),
// but with 1024-thread blocks: 16 waves x 2 blocks/CU (2x64KB LDS = 128KB
// of 160KB) = 32 waves/CU = 100% occupancy ceiling, vs R4's 39%.
// Each block = one (b, pi, pj, group) = 4 ch x 64x64 patch = 16384 floats;
// each thread owns 4 float4, one per channel plane: a = a0 + k*65536.

constexpr int CHANNELS = 128;
constexpr int HW = 256;
constexpr int NP = 4;
constexpr int G = 32;
constexpr int CPG = CHANNELS / G;          // 4 channels per group
constexpr float EPS = 1e-5f;

typedef float f32x4 __attribute__((ext_vector_type(4)));

__device__ __forceinline__ float fast_gate(float v) {
    // 1 + silu(v) = 1 + v / (1 + exp(-v)); exp(-v) = exp2(-v*log2(e))
    const float e = __builtin_amdgcn_exp2f(v * -1.44269504088896f);
    return 1.0f + v * __builtin_amdgcn_rcpf(1.0f + e);
}

__global__ __launch_bounds__(1024, 8)
void gn_patch_gate_kernel(const float* __restrict__ x,
                          const float* __restrict__ y,
                          const float* __restrict__ wgt,
                          const float* __restrict__ bvec,
                          float* __restrict__ out)
{
    __shared__ float4 xs[4096];     // 64 KB: the whole group's x tile
    __shared__ float red[32];

    const int bid = blockIdx.x;
    const int g  = bid & 31;          // group
    const int pj = (bid >> 5) & 3;    // patch col
    const int pi = (bid >> 7) & 3;    // patch row
    const int b  = bid >> 9;          // batch
    const int tid = threadIdx.x;

    const unsigned base =
        (((unsigned)b * CHANNELS + (unsigned)g * CPG) * HW + (unsigned)pi * 64) * HW
        + (unsigned)pj * 64;
    // 1024 threads cover one full 64x64 plane in float4s:
    // row = tid>>4 in [0,64), col4 = tid&15.
    const unsigned a0 = base + (((unsigned)tid >> 4) << 8) + (((unsigned)tid & 15) << 2);

    // Phase 1: load x (one channel plane per k) -> LDS, accumulate sums.
    float s = 0.f, ss = 0.f;
#pragma unroll
    for (int k = 0; k < 4; ++k) {
        const unsigned a = a0 + (unsigned)(k << 16);        // k * 65536
        const float4 v = *reinterpret_cast<const float4*>(x + a);
        xs[(unsigned)tid + (unsigned)(k << 10)] = v;
        s  += (v.x + v.y) + (v.z + v.w);
        ss += (v.x * v.x + v.y * v.y) + (v.z * v.z + v.w * v.w);
    }

    // Wave (64-lane) butterfly reduce, then cross-wave via LDS.
#pragma unroll
    for (int off = 32; off; off >>= 1) {
        s  += __shfl_xor(s, off);
        ss += __shfl_xor(ss, off);
    }
    const int wv = tid >> 6;          // 16 waves
    if ((tid & 63) == 0) { red[wv] = s; red[16 + wv] = ss; }
    __syncthreads();
    float ts = 0.f, tss = 0.f;
#pragma unroll
    for (int q = 0; q < 16; ++q) { ts += red[q]; tss += red[16 + q]; }

    const float inv_n = 1.0f / 16384.0f;
    const float mean = ts * inv_n;
    const float var  = fmaxf(tss * inv_n - mean * mean, 0.f);
    const float rstd = rsqrtf(var + EPS);

    // Per-channel affine folded into scale/shift (channel index == k).
    float scl[CPG], sft[CPG];
#pragma unroll
    for (int cc = 0; cc < CPG; ++cc) {
        const float wc = wgt[g * CPG + cc];
        scl[cc] = wc * rstd;
        sft[cc] = bvec[g * CPG + cc] - mean * rstd * wc;
    }

    // Phase 2: normalize from LDS, gate with y, NT store.
#pragma unroll
    for (int k = 0; k < 4; ++k) {
        const unsigned a = a0 + (unsigned)(k << 16);
        const float4 v = xs[(unsigned)tid + (unsigned)(k << 10)];
        const float4 w = *reinterpret_cast<const float4*>(y + a);
        f32x4 o;
        o.x = (v.x * scl[k] + sft[k]) * fast_gate(w.x);
        o.y = (v.y * scl[k] + sft[k]) * fast_gate(w.y);
        o.z = (v.z * scl[k] + sft[k]) * fast_gate(w.z);
        o.w = (v.w * scl[k] + sft[k]) * fast_gate(w.w);
        __builtin_nontemporal_store(o, reinterpret_cast<f32x4*>(out + a));
    }
}

extern "C" void kernel_launch(void* const* d_in, const int* in_sizes, int n_in,
                              void* d_out, int out_size, void* d_ws, size_t ws_size,
                              hipStream_t stream) {
    const float* x    = (const float*)d_in[0];
    const float* y    = (const float*)d_in[1];
    const float* wgt  = (const float*)d_in[2];
    const float* bvec = (const float*)d_in[3];
    float* out = (float*)d_out;

    const int B = in_sizes[0] / (CHANNELS * HW * HW);   // 8
    const int nblocks = B * NP * NP * G;                // 4096
    gn_patch_gate_kernel<<<dim3(nblocks), dim3(1024), 0, stream>>>(x, y, wgt, bvec, out);
}